// Round 1
// baseline (9438.413 us; speedup 1.0000x reference)
//
#include <hip/hip_runtime.h>
#include <math.h>

typedef unsigned short ushort_t;
typedef unsigned int uint32;

// Problem constants (GPT-2 small-ish: L=6, B=2, T=1024, C=768, H=12, F=3072, V=50257)
constexpr int kL = 6;
constexpr int kB = 2;
constexpr int kT = 1024;
constexpr int kC = 768;
constexpr int kH = 12;
constexpr int kD = 64;
constexpr int kF = 3072;
constexpr int kV = 50257;
constexpr int kM = kB * kT;   // 2048 rows everywhere

__device__ __forceinline__ float bf2f(ushort_t u) {
    return __uint_as_float(((uint32)u) << 16);
}
__device__ __forceinline__ ushort_t f2bf(float f) {
    uint32 u = __float_as_uint(f);
    u += 0x7fffu + ((u >> 16) & 1u);   // RNE
    return (ushort_t)(u >> 16);
}

typedef __bf16 bf16x8 __attribute__((ext_vector_type(8)));
typedef float f32x4 __attribute__((ext_vector_type(4)));

// ---------------------------------------------------------------- embedding
__global__ __launch_bounds__(256)
void embed_kernel(const int* __restrict__ idx, const float* __restrict__ wte,
                  const float* __restrict__ pte, float* __restrict__ x)
{
    const int row = blockIdx.x;            // 0..kM-1
    const int tpos = row & (kT - 1);       // row % T
    const int id = idx[row];
    const int t = threadIdx.x;
#pragma unroll
    for (int c = 0; c < 3; ++c) {
        int col = t + c * 256;
        x[(size_t)row * kC + col] = wte[(size_t)id * kC + col] + pte[(size_t)tpos * kC + col];
    }
}

// ---------------------------------------------------------------- layernorm
__global__ __launch_bounds__(256)
void ln_kernel(const float* __restrict__ x, const float* __restrict__ s,
               const float* __restrict__ bia, ushort_t* __restrict__ out)
{
    __shared__ float red[4];
    const int row = blockIdx.x;
    const int t = threadIdx.x;
    const float* xr = x + (size_t)row * kC;
    float v0 = xr[t], v1 = xr[t + 256], v2 = xr[t + 512];
    float sum = v0 + v1 + v2;
#pragma unroll
    for (int o = 32; o > 0; o >>= 1) sum += __shfl_xor(sum, o);
    if ((t & 63) == 0) red[t >> 6] = sum;
    __syncthreads();
    float mu = (red[0] + red[1] + red[2] + red[3]) * (1.f / kC);
    __syncthreads();
    float d0 = v0 - mu, d1 = v1 - mu, d2 = v2 - mu;
    float vs = d0 * d0 + d1 * d1 + d2 * d2;
#pragma unroll
    for (int o = 32; o > 0; o >>= 1) vs += __shfl_xor(vs, o);
    if ((t & 63) == 0) red[t >> 6] = vs;
    __syncthreads();
    float rstd = rsqrtf((red[0] + red[1] + red[2] + red[3]) * (1.f / kC) + 1e-5f);
    ushort_t* orow = out + (size_t)row * kC;
    orow[t]       = f2bf(d0 * rstd * s[t]       + bia[t]);
    orow[t + 256] = f2bf(d1 * rstd * s[t + 256] + bia[t + 256]);
    orow[t + 512] = f2bf(d2 * rstd * s[t + 512] + bia[t + 512]);
}

// ---------------------------------------------------------------- attention
// one block per (q, head, batch); qkv is bf16 [B*T, 3C]
__global__ __launch_bounds__(256)
void attn_kernel(const ushort_t* __restrict__ qkv, ushort_t* __restrict__ atto)
{
    const int qi = blockIdx.x;
    const int h  = blockIdx.y;
    const int b  = blockIdx.z;
    const int t  = threadIdx.x;
    __shared__ float qv[64];
    __shared__ float sc[kT];
    __shared__ float red[4];
    __shared__ float obuf[4][64];

    const size_t rs = 3 * kC;
    const ushort_t* base = qkv + (size_t)(b * kT) * rs;
    if (t < 64) qv[t] = bf2f(base[(size_t)qi * rs + h * 64 + t]) * 0.125f; // 1/sqrt(64)
    __syncthreads();

    float lmax = -3.0e38f;
    for (int k = t; k <= qi; k += 256) {
        const uint32* kp = (const uint32*)(base + (size_t)k * rs + kC + h * 64);
        float s = 0.f;
#pragma unroll
        for (int c = 0; c < 32; ++c) {
            uint32 u = kp[c];
            s += qv[2 * c]     * __uint_as_float(u << 16);
            s += qv[2 * c + 1] * __uint_as_float(u & 0xffff0000u);
        }
        sc[k] = s;
        lmax = fmaxf(lmax, s);
    }
#pragma unroll
    for (int o = 32; o > 0; o >>= 1) lmax = fmaxf(lmax, __shfl_xor(lmax, o));
    if ((t & 63) == 0) red[t >> 6] = lmax;
    __syncthreads();
    float bmax = fmaxf(fmaxf(red[0], red[1]), fmaxf(red[2], red[3]));
    __syncthreads();

    float lsum = 0.f;
    for (int k = t; k <= qi; k += 256) {
        float p = __expf(sc[k] - bmax);
        sc[k] = p;
        lsum += p;
    }
#pragma unroll
    for (int o = 32; o > 0; o >>= 1) lsum += __shfl_xor(lsum, o);
    if ((t & 63) == 0) red[t >> 6] = lsum;
    __syncthreads();                       // also orders sc[] prob writes
    float inv = 1.f / (red[0] + red[1] + red[2] + red[3]);

    const int d  = t & 63;
    const int sl = t >> 6;
    float o = 0.f;
    for (int k = sl; k <= qi; k += 4) {
        o += sc[k] * bf2f(base[(size_t)k * rs + 2 * kC + h * 64 + d]);
    }
    obuf[sl][d] = o;
    __syncthreads();
    if (t < 64) {
        float r = (obuf[0][t] + obuf[1][t] + obuf[2][t] + obuf[3][t]) * inv;
        atto[((size_t)(b * kT) + qi) * kC + h * 64 + t] = f2bf(r);
    }
}

// ---------------------------------------------------------------- GEMM
// Out[M,N] = A(bf16,[M,K]) @ W(f32,[K,N]) [+bias] [gelu] [+resid(f32,[M,N])]
// 128x128 tile, 4 waves, mfma_f32_16x16x32_bf16.
constexpr int BM = 128;
constexpr int BN = 128;
constexpr int BK = 32;
constexpr int LDA = BK + 8;   // 40 (pad breaks pow2 strides)
constexpr int LDB = BK + 8;

template <int HAS_BIAS, int HAS_RES, int DO_GELU, int OUT_BF16>
__global__ __launch_bounds__(256)
void gemm_kernel(const ushort_t* __restrict__ A, const float* __restrict__ W,
                 const float* __restrict__ bias, const float* __restrict__ resid,
                 float* __restrict__ outF, ushort_t* __restrict__ outB,
                 int M, int N, int K)
{
    __shared__ ushort_t As[BM * LDA];
    __shared__ ushort_t Bs[BN * LDB];
    const int t  = threadIdx.x;
    const int m0 = blockIdx.x * BM;
    const int n0 = blockIdx.y * BN;
    const int lane = t & 63;
    const int wv = t >> 6;
    const int wr = (wv & 1) * 64;
    const int wc = (wv >> 1) * 64;
    const int lr = lane & 15;
    const int ks = (lane >> 4) * 8;

    f32x4 acc[4][4] = {};

    const int nkt = K / BK;
    for (int kt = 0; kt < nkt; ++kt) {
        // stage A: 128x32 bf16, 16B chunks
#pragma unroll
        for (int c = 0; c < 2; ++c) {
            int id = t + c * 256;
            int row = id >> 2;
            int ko = (id & 3) * 8;
            const ushort_t* ga = A + (size_t)(m0 + row) * K + kt * BK + ko;
            *(uint4*)&As[row * LDA + ko] = *(const uint4*)ga;
        }
        // stage B: 32x128 f32 -> bf16, transposed into Bs[n][k]
#pragma unroll
        for (int c = 0; c < 16; ++c) {
            int e = t + c * 256;
            int k = e >> 7;
            int n = e & 127;
            int gn = n0 + n;
            float w = 0.f;
            if (gn < N) w = W[(size_t)(kt * BK + k) * N + gn];
            Bs[n * LDB + k] = f2bf(w);
        }
        __syncthreads();
        bf16x8 af[4], bfr[4];
#pragma unroll
        for (int i = 0; i < 4; ++i)
            af[i] = *(const bf16x8*)&As[(wr + i * 16 + lr) * LDA + ks];
#pragma unroll
        for (int j = 0; j < 4; ++j)
            bfr[j] = *(const bf16x8*)&Bs[(wc + j * 16 + lr) * LDB + ks];
#pragma unroll
        for (int i = 0; i < 4; ++i)
#pragma unroll
            for (int j = 0; j < 4; ++j)
                acc[i][j] = __builtin_amdgcn_mfma_f32_16x16x32_bf16(af[i], bfr[j], acc[i][j], 0, 0, 0);
        __syncthreads();
    }

    // epilogue: D row = (lane>>4)*4 + r, col = lane&15  (verified gfx950 mapping)
    const int rbase = m0 + wr + (lane >> 4) * 4;
    const int cbase = n0 + wc + (lane & 15);
#pragma unroll
    for (int j = 0; j < 4; ++j) {
        int gn = cbase + j * 16;
        if (gn >= N) continue;
        float bv = HAS_BIAS ? bias[gn] : 0.f;
#pragma unroll
        for (int i = 0; i < 4; ++i) {
#pragma unroll
            for (int r = 0; r < 4; ++r) {
                int gm = rbase + i * 16 + r;
                float v = acc[i][j][r] + bv;
                if (DO_GELU) v = 0.5f * v * (1.f + erff(v * 0.70710678118f));
                if (HAS_RES) v += resid[(size_t)gm * N + gn];
                if (OUT_BF16) outB[(size_t)gm * N + gn] = f2bf(v);
                else          outF[(size_t)gm * N + gn] = v;
            }
        }
    }
}

// ---------------------------------------------------------------- launch
extern "C" void kernel_launch(void* const* d_in, const int* in_sizes, int n_in,
                              void* d_out, int out_size, void* d_ws, size_t ws_size,
                              hipStream_t stream)
{
    const int*   idx    = (const int*)  d_in[0];
    const float* wte    = (const float*)d_in[1];
    const float* pte    = (const float*)d_in[2];
    const float* ln1_s  = (const float*)d_in[3];
    const float* ln1_b  = (const float*)d_in[4];
    const float* qkv_w  = (const float*)d_in[5];
    const float* qkv_b  = (const float*)d_in[6];
    const float* proj_w = (const float*)d_in[7];
    const float* proj_b = (const float*)d_in[8];
    const float* ln2_s  = (const float*)d_in[9];
    const float* ln2_b  = (const float*)d_in[10];
    const float* w1     = (const float*)d_in[11];
    const float* b1     = (const float*)d_in[12];
    const float* w2     = (const float*)d_in[13];
    const float* b2     = (const float*)d_in[14];
    const float* lnf_s  = (const float*)d_in[15];
    const float* lnf_b  = (const float*)d_in[16];
    const float* head_w = (const float*)d_in[17];
    float* out = (float*)d_out;

    // workspace carve (all 16B-aligned)
    char* p = (char*)d_ws;
    float*    x    = (float*)p;     p += (size_t)kM * kC * 4;        // f32 residual stream
    ushort_t* h    = (ushort_t*)p;  p += (size_t)kM * kC * 2;        // LN output (bf16)
    ushort_t* qkvb = (ushort_t*)p;  p += (size_t)kM * 3 * kC * 2;    // qkv (bf16)
    ushort_t* atto = (ushort_t*)p;  p += (size_t)kM * kC * 2;        // attn out (bf16)
    ushort_t* mlpf = (ushort_t*)p;  p += (size_t)kM * kF * 2;        // gelu(mlp1) (bf16)

    embed_kernel<<<kM, 256, 0, stream>>>(idx, wte, pte, x);

    for (int l = 0; l < kL; ++l) {
        ln_kernel<<<kM, 256, 0, stream>>>(x, ln1_s + l * kC, ln1_b + l * kC, h);
        gemm_kernel<1, 0, 0, 1><<<dim3(kM / BM, (3 * kC) / BN), 256, 0, stream>>>(
            h, qkv_w + (size_t)l * kC * 3 * kC, qkv_b + l * 3 * kC,
            nullptr, nullptr, qkvb, kM, 3 * kC, kC);
        attn_kernel<<<dim3(kT, kH, kB), 256, 0, stream>>>(qkvb, atto);
        gemm_kernel<1, 1, 0, 0><<<dim3(kM / BM, kC / BN), 256, 0, stream>>>(
            atto, proj_w + (size_t)l * kC * kC, proj_b + l * kC,
            x, x, nullptr, kM, kC, kC);
        ln_kernel<<<kM, 256, 0, stream>>>(x, ln2_s + l * kC, ln2_b + l * kC, h);
        gemm_kernel<1, 0, 1, 1><<<dim3(kM / BM, kF / BN), 256, 0, stream>>>(
            h, w1 + (size_t)l * kC * kF, b1 + l * kF,
            nullptr, nullptr, mlpf, kM, kF, kC);
        gemm_kernel<1, 1, 0, 0><<<dim3(kM / BM, kC / BN), 256, 0, stream>>>(
            mlpf, w2 + (size_t)l * kF * kC, b2 + l * kC,
            x, x, nullptr, kM, kC, kF);
    }

    ln_kernel<<<kM, 256, 0, stream>>>(x, lnf_s, lnf_b, h);
    gemm_kernel<0, 0, 0, 0><<<dim3(kM / BM, (kV + BN - 1) / BN), 256, 0, stream>>>(
        h, head_w, nullptr, nullptr, out, nullptr, kM, kV, kC);
}